// Round 8
// baseline (303.539 us; speedup 1.0000x reference)
//
#include <hip/hip_runtime.h>

typedef int i32x4 __attribute__((ext_vector_type(4)));

#define AS1 __attribute__((address_space(1)))
#define AS3 __attribute__((address_space(3)))

#define M_DIM 8192
#define N_DIM 8192
#define K_DIM 2048
#define NT 32   // K-tiles of 64 bytes

// ---------------- quantize x: per-tensor scale, 16 elems/thread ----------------
__global__ __launch_bounds__(256) void quant_x_kernel(
    const float* __restrict__ x, const float* __restrict__ in_scale,
    i32x4* __restrict__ qx, int n16)
{
    int idx = blockIdx.x * 256 + threadIdx.x;
    if (idx >= n16) return;
    float s = in_scale[0];
    const float4* xp = reinterpret_cast<const float4*>(x) + (size_t)idx * 4;
    union { char c[16]; i32x4 v; } u;
#pragma unroll
    for (int v4 = 0; v4 < 4; ++v4) {
        float4 f = xp[v4];
        u.c[v4*4+0] = (char)(int)fminf(fmaxf(rintf(f.x / s), -128.f), 127.f);
        u.c[v4*4+1] = (char)(int)fminf(fmaxf(rintf(f.y / s), -128.f), 127.f);
        u.c[v4*4+2] = (char)(int)fminf(fmaxf(rintf(f.z / s), -128.f), 127.f);
        u.c[v4*4+3] = (char)(int)fminf(fmaxf(rintf(f.w / s), -128.f), 127.f);
    }
    qx[idx] = u.v;
}

// ---------------- quantize w: per-row (out-channel) scale ----------------
__global__ __launch_bounds__(256) void quant_w_kernel(
    const float* __restrict__ w, const float* __restrict__ w_scale,
    i32x4* __restrict__ qw, int n16)
{
    int idx = blockIdx.x * 256 + threadIdx.x;
    if (idx >= n16) return;
    float s = w_scale[idx >> 7];   // K=2048 -> 128 threads (of 16 elems) per row
    const float4* wp = reinterpret_cast<const float4*>(w) + (size_t)idx * 4;
    union { char c[16]; i32x4 v; } u;
#pragma unroll
    for (int v4 = 0; v4 < 4; ++v4) {
        float4 f = wp[v4];
        u.c[v4*4+0] = (char)(int)fminf(fmaxf(rintf(f.x / s), -128.f), 127.f);
        u.c[v4*4+1] = (char)(int)fminf(fmaxf(rintf(f.y / s), -128.f), 127.f);
        u.c[v4*4+2] = (char)(int)fminf(fmaxf(rintf(f.z / s), -128.f), 127.f);
        u.c[v4*4+3] = (char)(int)fminf(fmaxf(rintf(f.w / s), -128.f), 127.f);
    }
    qw[idx] = u.v;
}

// ---------------- per-out-channel combined scale + dequantized bias ----------------
__global__ __launch_bounds__(256) void prep_kernel(
    const float* __restrict__ bias, const float* __restrict__ in_scale,
    const float* __restrict__ w_scale, const float* __restrict__ b_scale,
    float* __restrict__ oscale, float* __restrict__ obias, int n)
{
    int i = blockIdx.x * 256 + threadIdx.x;
    if (i >= n) return;
    oscale[i] = in_scale[0] * w_scale[i] * 0.5f;   // W_ALPHA
    float bs = b_scale[i];
    float q = fminf(fmaxf(rintf(bias[i] / bs), -128.f), 127.f);
    obias[i] = q * bs * 0.75f;                      // B_BETA
}

// ---------------- int8 GEMM: 256x256 tile; A via LDS (2-deep), B direct global->reg ----
// 8 waves (2M x 4N), per-wave 128x64 output = 8x4 frags of mfma_i32_16x16x64_i8.
// LDS traffic cut 37% vs R2-R7 (the schedule-invariant bottleneck): B fragments are
// loaded straight from global (wave = 16 consecutive rows x 64 B = 16 full cache
// lines, L2-resident panel) into registers, ping-ponged, prefetched 1 tile ahead.
// LDS is A-only: 16 KB staged + 64 KB read per K-tile (< MFMA 1306 cy).
// LDS: 2 bufs x 16 KB = 32 KiB. Swizzle slot' = kg ^ ((row>>1)&3), inverse-swizzled
// global src (rule 21) -> 0 bank conflicts (verified R2).
// Ring safety: a wave's ds_reads retire before its MFMAs issue (in-order issue +
// lgkm waits), which precede its barrier arrival; stage(t+1) writes the opposite
// buffer; stage(t+2) (issued after t's closing barrier) is therefore safe.
// NOTE: min-waves-per-EU MUST stay 2 — acc=128 regs; bound of 4 spills (R3: 6x).
__global__ __launch_bounds__(512, 2) void gemm_i8_kernel(
    const char* __restrict__ qx,   // [M][K] int8
    const char* __restrict__ qw,   // [N][K] int8
    const float* __restrict__ oscale,
    const float* __restrict__ obias,
    float* __restrict__ out)       // [M][N] fp32
{
    __shared__ __align__(16) char ldsA[2 * 16384];

    const int t    = threadIdx.x;          // 0..511
    const int lane = t & 63;
    const int wid  = t >> 6;               // 0..7
    const int wm   = wid >> 2;             // 0..1
    const int wn   = wid & 3;              // 0..3

    // XCD-aware swizzle: 1024 blocks, 1024 % 8 == 0 -> bijective
    int bid = blockIdx.x;
    int sid = (bid & 7) * 128 + (bid >> 3);
    const size_t brow = (size_t)(sid >> 5) * 256;
    const size_t bcol = (size_t)(sid & 31) * 256;

    // A staging: thread t covers LDS row t/4 (+128 on 2nd call), 16B slot t&3.
    // Global source pre-swizzled: logical slot = (t&3) ^ ((t>>3)&3)  (rule 21).
    const int srow  = t >> 2;
    const int lslot = (t & 3) ^ ((t >> 3) & 3);
    const char* gA = qx + (brow + srow) * K_DIM + lslot * 16;
    char* dstA = ldsA + t * 16;

#define STAGE_A(tt_) do {                                                                 \
    __builtin_amdgcn_global_load_lds((const AS1 unsigned int*)(gA + (tt_) * 64),          \
        (AS3 unsigned int*)(dstA + ((tt_) & 1) * 16384), 16, 0, 0);                       \
    __builtin_amdgcn_global_load_lds((const AS1 unsigned int*)(gA + (tt_) * 64 + 128 * K_DIM), \
        (AS3 unsigned int*)(dstA + ((tt_) & 1) * 16384 + 8192), 16, 0, 0);                \
  } while (0)

    // A-frag LDS read base (swizzled). Swizzle term invariant under row += 16*m,
    // so frag m = offA0 + m*1024 (compile-time immediates).
    const int lrow = lane & 15;
    const int kg   = lane >> 4;            // 16B k-group 0..3
    const int rA   = wm * 128 + lrow;
    const int offA0 = rA * 64 + ((kg ^ ((rA >> 1) & 3)) * 16);

    // B-frag global base: lane reads 16B at row (bcol + wn*64 + n*16 + lrow),
    // k-offset kg*16; frag n offset = n*16 rows = n*32768 B; tile tt offset = tt*64.
    const char* gBf = qw + (bcol + (size_t)wn * 64 + lrow) * K_DIM + kg * 16;

    i32x4 acc[8][4];
#pragma unroll
    for (int m = 0; m < 8; ++m)
#pragma unroll
        for (int n = 0; n < 4; ++n)
            acc[m][n] = (i32x4){0, 0, 0, 0};

#define MM(m_, n_, a_, b_) acc[m_][n_] = __builtin_amdgcn_mfma_i32_16x16x64_i8((a_), (b_), acc[m_][n_], 0, 0, 0)
#define BAR() do { __builtin_amdgcn_s_barrier(); asm volatile("" ::: "memory"); } while (0)
#define VMCNT0() asm volatile("s_waitcnt vmcnt(0)" ::: "memory")
#define LOADB(tt_, BN0, BN1, BN2, BN3) do {                                               \
    const char* gBt_ = gBf + (tt_) * 64;                                                  \
    BN0 = *(const i32x4*)(gBt_);                                                          \
    BN1 = *(const i32x4*)(gBt_ + 32768);                                                  \
    BN2 = *(const i32x4*)(gBt_ + 65536);                                                  \
    BN3 = *(const i32x4*)(gBt_ + 98304);                                                  \
  } while (0)

    // K-tile body: prefetch (stage A(t+1) + load B(t+1) into BN), read 8 A frags,
    // 32 MFMA with current B regs, then vmcnt(0) + barrier (certify A(t+1)).
#define KT(tt_, BC0,BC1,BC2,BC3, BN0,BN1,BN2,BN3, PF_) do {                               \
    const char* bAp = ldsA + ((tt_) & 1) * 16384;                                         \
    if (PF_) { STAGE_A((tt_) + 1); LOADB((tt_) + 1, BN0, BN1, BN2, BN3); }                \
    i32x4 a0 = *(const i32x4*)(bAp + offA0);                                              \
    i32x4 a1 = *(const i32x4*)(bAp + offA0 + 1024);                                       \
    i32x4 a2 = *(const i32x4*)(bAp + offA0 + 2048);                                       \
    i32x4 a3 = *(const i32x4*)(bAp + offA0 + 3072);                                       \
    i32x4 a4 = *(const i32x4*)(bAp + offA0 + 4096);                                       \
    i32x4 a5 = *(const i32x4*)(bAp + offA0 + 5120);                                       \
    i32x4 a6 = *(const i32x4*)(bAp + offA0 + 6144);                                       \
    i32x4 a7 = *(const i32x4*)(bAp + offA0 + 7168);                                       \
    __builtin_amdgcn_s_setprio(1);                                                        \
    MM(0,0,a0,BC0); MM(0,1,a0,BC1); MM(0,2,a0,BC2); MM(0,3,a0,BC3);                       \
    MM(1,0,a1,BC0); MM(1,1,a1,BC1); MM(1,2,a1,BC2); MM(1,3,a1,BC3);                       \
    MM(2,0,a2,BC0); MM(2,1,a2,BC1); MM(2,2,a2,BC2); MM(2,3,a2,BC3);                       \
    MM(3,0,a3,BC0); MM(3,1,a3,BC1); MM(3,2,a3,BC2); MM(3,3,a3,BC3);                       \
    MM(4,0,a4,BC0); MM(4,1,a4,BC1); MM(4,2,a4,BC2); MM(4,3,a4,BC3);                       \
    MM(5,0,a5,BC0); MM(5,1,a5,BC1); MM(5,2,a5,BC2); MM(5,3,a5,BC3);                       \
    MM(6,0,a6,BC0); MM(6,1,a6,BC1); MM(6,2,a6,BC2); MM(6,3,a6,BC3);                       \
    MM(7,0,a7,BC0); MM(7,1,a7,BC1); MM(7,2,a7,BC2); MM(7,3,a7,BC3);                       \
    __builtin_amdgcn_s_setprio(0);                                                        \
    if (PF_) { VMCNT0(); BAR(); }                                                         \
  } while (0)

    // prologue: stage A(0), load B(0); drain; barrier certifies A(0)
    i32x4 Bx0, Bx1, Bx2, Bx3, By0, By1, By2, By3;
    STAGE_A(0);
    LOADB(0, Bx0, Bx1, Bx2, Bx3);
    VMCNT0();
    BAR();

    for (int it = 0; it < 15; ++it) {      // tiles 0..29
        const int t0 = 2 * it;
        KT(t0,     Bx0,Bx1,Bx2,Bx3, By0,By1,By2,By3, 1);
        KT(t0 + 1, By0,By1,By2,By3, Bx0,Bx1,Bx2,Bx3, 1);
    }
    KT(30, Bx0,Bx1,Bx2,Bx3, By0,By1,By2,By3, 1);   // stages A(31), loads B(31)
    KT(31, By0,By1,By2,By3, Bx0,Bx1,Bx2,Bx3, 0);   // no prefetch, no trailing sync

#undef KT
#undef LOADB
#undef STAGE_A
#undef MM
#undef BAR
#undef VMCNT0

    // epilogue: C/D layout col = lane&15, row = (lane>>4)*4 + j
    const int colq = lane & 15;
    const int rowq = lane >> 4;
#pragma unroll
    for (int n = 0; n < 4; ++n) {
        size_t col = bcol + wn * 64 + n * 16 + colq;
        float sc = oscale[col];
        float bi = obias[col];
#pragma unroll
        for (int m = 0; m < 8; ++m) {
            size_t rbase = brow + wm * 128 + m * 16 + (size_t)rowq * 4;
#pragma unroll
            for (int j = 0; j < 4; ++j)
                out[(rbase + j) * N_DIM + col] = (float)acc[m][n][j] * sc + bi;
        }
    }
}

extern "C" void kernel_launch(void* const* d_in, const int* in_sizes, int n_in,
                              void* d_out, int out_size, void* d_ws, size_t ws_size,
                              hipStream_t stream) {
    const float* x        = (const float*)d_in[0];
    const float* weight   = (const float*)d_in[1];
    const float* bias     = (const float*)d_in[2];
    const float* in_scale = (const float*)d_in[3];
    const float* w_scale  = (const float*)d_in[4];
    const float* b_scale  = (const float*)d_in[5];
    float* out = (float*)d_out;

    char* ws = (char*)d_ws;
    const size_t xk = (size_t)M_DIM * K_DIM;
    const size_t wk = (size_t)N_DIM * K_DIM;
    char*  qx     = ws;
    char*  qw     = ws + xk;
    float* oscale = (float*)(ws + xk + wk);
    float* obias  = oscale + N_DIM;

    const int n16 = (int)(xk / 16);   // 1,048,576 = 4096 * 256
    quant_x_kernel<<<4096, 256, 0, stream>>>(x, in_scale, (i32x4*)qx, n16);
    quant_w_kernel<<<4096, 256, 0, stream>>>(weight, w_scale, (i32x4*)qw, n16);
    prep_kernel<<<32, 256, 0, stream>>>(bias, in_scale, w_scale, b_scale, oscale, obias, N_DIM);

    gemm_i8_kernel<<<1024, 512, 0, stream>>>(qx, qw, oscale, obias, out);
}

// Round 9
// 253.352 us; speedup vs baseline: 1.1981x; 1.1981x over previous
//
#include <hip/hip_runtime.h>

typedef int i32x4  __attribute__((ext_vector_type(4)));
typedef int i32x16 __attribute__((ext_vector_type(16)));

#define AS1 __attribute__((address_space(1)))
#define AS3 __attribute__((address_space(3)))

#define M_DIM 8192
#define N_DIM 8192
#define K_DIM 2048
#define NT 32   // K-tiles of 64 bytes

// ---------------- quantize x: per-tensor scale, 16 elems/thread ----------------
__global__ __launch_bounds__(256) void quant_x_kernel(
    const float* __restrict__ x, const float* __restrict__ in_scale,
    i32x4* __restrict__ qx, int n16)
{
    int idx = blockIdx.x * 256 + threadIdx.x;
    if (idx >= n16) return;
    float s = in_scale[0];
    const float4* xp = reinterpret_cast<const float4*>(x) + (size_t)idx * 4;
    union { char c[16]; i32x4 v; } u;
#pragma unroll
    for (int v4 = 0; v4 < 4; ++v4) {
        float4 f = xp[v4];
        u.c[v4*4+0] = (char)(int)fminf(fmaxf(rintf(f.x / s), -128.f), 127.f);
        u.c[v4*4+1] = (char)(int)fminf(fmaxf(rintf(f.y / s), -128.f), 127.f);
        u.c[v4*4+2] = (char)(int)fminf(fmaxf(rintf(f.z / s), -128.f), 127.f);
        u.c[v4*4+3] = (char)(int)fminf(fmaxf(rintf(f.w / s), -128.f), 127.f);
    }
    qx[idx] = u.v;
}

// ---------------- quantize w: per-row (out-channel) scale ----------------
__global__ __launch_bounds__(256) void quant_w_kernel(
    const float* __restrict__ w, const float* __restrict__ w_scale,
    i32x4* __restrict__ qw, int n16)
{
    int idx = blockIdx.x * 256 + threadIdx.x;
    if (idx >= n16) return;
    float s = w_scale[idx >> 7];   // K=2048 -> 128 threads (of 16 elems) per row
    const float4* wp = reinterpret_cast<const float4*>(w) + (size_t)idx * 4;
    union { char c[16]; i32x4 v; } u;
#pragma unroll
    for (int v4 = 0; v4 < 4; ++v4) {
        float4 f = wp[v4];
        u.c[v4*4+0] = (char)(int)fminf(fmaxf(rintf(f.x / s), -128.f), 127.f);
        u.c[v4*4+1] = (char)(int)fminf(fmaxf(rintf(f.y / s), -128.f), 127.f);
        u.c[v4*4+2] = (char)(int)fminf(fmaxf(rintf(f.z / s), -128.f), 127.f);
        u.c[v4*4+3] = (char)(int)fminf(fmaxf(rintf(f.w / s), -128.f), 127.f);
    }
    qw[idx] = u.v;
}

// ---------------- per-out-channel combined scale + dequantized bias ----------------
__global__ __launch_bounds__(256) void prep_kernel(
    const float* __restrict__ bias, const float* __restrict__ in_scale,
    const float* __restrict__ w_scale, const float* __restrict__ b_scale,
    float* __restrict__ oscale, float* __restrict__ obias, int n)
{
    int i = blockIdx.x * 256 + threadIdx.x;
    if (i >= n) return;
    oscale[i] = in_scale[0] * w_scale[i] * 0.5f;   // W_ALPHA
    float bs = b_scale[i];
    float q = fminf(fmaxf(rintf(bias[i] / bs), -128.f), 127.f);
    obias[i] = q * bs * 0.75f;                      // B_BETA
}

// ---------------- int8 GEMM: 128x128 tile, 32x32x32 MFMA, 3 blocks/CU ----------------
// 4 waves (2M x 2N), per-wave 64x64 output = 2x2 tiles of mfma_i32_32x32x32_i8
// (acc 2x2x16 = 64 VGPR — half of the 256^2 design, so 3 independent blocks/CU
// co-reside: the m97/m114 cross-block TLP that every 256^2 round lacked).
// LDS: 2 bufs x (A 8KB + B 8KB) = 32 KiB, double-buffered, one vmcnt(0)+barrier
// per tile (drain hidden by the other blocks' MFMA).
// Swizzle: 16B-slot' = slot ^ ((row>>1)&3), inverse-swizzled global src (rule 21);
// 32-row b128 read pattern = 8 accesses/bank (BW-uniform).
// A-operand layout (32x32x32 i8): row = lane&31, k = (lane>>5)*16 + e.
// C/D layout (32x32): col = lane&31, row = (reg&3) + 8*(reg>>2) + 4*(lane>>5).
__global__ __launch_bounds__(256, 3) void gemm_i8_kernel(
    const char* __restrict__ qx,   // [M][K] int8
    const char* __restrict__ qw,   // [N][K] int8
    const float* __restrict__ oscale,
    const float* __restrict__ obias,
    float* __restrict__ out)       // [M][N] fp32
{
    __shared__ __align__(16) char ldsA[2 * 8192];
    __shared__ __align__(16) char ldsB[2 * 8192];

    const int t    = threadIdx.x;          // 0..255
    const int lane = t & 63;
    const int wid  = t >> 6;               // 0..3
    const int wm   = wid >> 1;             // 0..1
    const int wn   = wid & 1;              // 0..1

    // XCD-aware swizzle: 4096 blocks, 4096 % 8 == 0 -> bijective
    int bid = blockIdx.x;
    int sid = (bid & 7) * 512 + (bid >> 3);
    const size_t brow = (size_t)(sid >> 6) * 128;
    const size_t bcol = (size_t)(sid & 63) * 128;

    // staging: thread t covers row t>>2 (+64 on 2nd call), 16B slot t&3 (linear dest).
    // Global source pre-swizzled: logical slot = (t&3) ^ ((row>>1)&3) = (t&3) ^ ((t>>3)&3).
    const int srow  = t >> 2;
    const int lslot = (t & 3) ^ ((t >> 3) & 3);
    const char* gA = qx + (brow + srow) * K_DIM + lslot * 16;
    const char* gB = qw + (bcol + srow) * K_DIM + lslot * 16;
    char* dstA = ldsA + t * 16;
    char* dstB = ldsB + t * 16;

#define STAGE(tt_) do {                                                                   \
    const int bb_ = ((tt_) & 1) * 8192; const int ko_ = (tt_) * 64;                       \
    __builtin_amdgcn_global_load_lds((const AS1 unsigned int*)(gA + ko_),                 \
        (AS3 unsigned int*)(dstA + bb_), 16, 0, 0);                                       \
    __builtin_amdgcn_global_load_lds((const AS1 unsigned int*)(gA + ko_ + 64 * K_DIM),    \
        (AS3 unsigned int*)(dstA + bb_ + 4096), 16, 0, 0);                                \
    __builtin_amdgcn_global_load_lds((const AS1 unsigned int*)(gB + ko_),                 \
        (AS3 unsigned int*)(dstB + bb_), 16, 0, 0);                                       \
    __builtin_amdgcn_global_load_lds((const AS1 unsigned int*)(gB + ko_ + 64 * K_DIM),    \
        (AS3 unsigned int*)(dstB + bb_ + 4096), 16, 0, 0);                                \
  } while (0)

    // per-lane fragment read offsets (swizzled): lane reads row r = w*64 + mt*32 + (l&31),
    // 16B slot = ks*2 + (l>>5), swizzled by ^((r>>1)&3).
    const int lrow = lane & 31;
    const int kg2  = lane >> 5;            // 0..1
    int offA[2][2], offB[2][2];
#pragma unroll
    for (int mt = 0; mt < 2; ++mt) {
        int r = wm * 64 + mt * 32 + lrow;
#pragma unroll
        for (int ks = 0; ks < 2; ++ks)
            offA[mt][ks] = r * 64 + (((ks * 2 + kg2) ^ ((r >> 1) & 3)) * 16);
    }
#pragma unroll
    for (int nt = 0; nt < 2; ++nt) {
        int r = wn * 64 + nt * 32 + lrow;
#pragma unroll
        for (int ks = 0; ks < 2; ++ks)
            offB[nt][ks] = r * 64 + (((ks * 2 + kg2) ^ ((r >> 1) & 3)) * 16);
    }

    i32x16 acc[2][2];
#pragma unroll
    for (int mt = 0; mt < 2; ++mt)
#pragma unroll
        for (int nt = 0; nt < 2; ++nt)
            acc[mt][nt] = (i32x16){0};

    // prologue: tile 0 staged and certified
    STAGE(0);
    asm volatile("s_waitcnt vmcnt(0)" ::: "memory");
    __syncthreads();

    for (int tt = 0; tt < NT; ++tt) {
        const char* bA = ldsA + (tt & 1) * 8192;
        const char* bB = ldsB + (tt & 1) * 8192;
        if (tt + 1 < NT) STAGE(tt + 1);

        i32x4 aF[2][2], bF[2][2];
#pragma unroll
        for (int mt = 0; mt < 2; ++mt)
#pragma unroll
            for (int ks = 0; ks < 2; ++ks)
                aF[mt][ks] = *(const i32x4*)(bA + offA[mt][ks]);
#pragma unroll
        for (int nt = 0; nt < 2; ++nt)
#pragma unroll
            for (int ks = 0; ks < 2; ++ks)
                bF[nt][ks] = *(const i32x4*)(bB + offB[nt][ks]);

#pragma unroll
        for (int mt = 0; mt < 2; ++mt)
#pragma unroll
            for (int nt = 0; nt < 2; ++nt)
#pragma unroll
                for (int ks = 0; ks < 2; ++ks)
                    acc[mt][nt] = __builtin_amdgcn_mfma_i32_32x32x32_i8(
                        aF[mt][ks], bF[nt][ks], acc[mt][nt], 0, 0, 0);

        if (tt + 1 < NT) {
            asm volatile("s_waitcnt vmcnt(0)" ::: "memory");
            __syncthreads();   // certifies tile tt+1; all reads of tt done -> tt+2 stage safe
        }
    }
#undef STAGE

    // epilogue: C/D 32x32 layout col = lane&31, row = (reg&3) + 8*(reg>>2) + 4*(lane>>5)
    const int colq = lane & 31;
    const int rbase4 = 4 * kg2;
#pragma unroll
    for (int nt = 0; nt < 2; ++nt) {
        size_t col = bcol + wn * 64 + nt * 32 + colq;
        float sc = oscale[col];
        float bi = obias[col];
#pragma unroll
        for (int mt = 0; mt < 2; ++mt) {
            size_t rtile = brow + wm * 64 + mt * 32 + rbase4;
#pragma unroll
            for (int rg = 0; rg < 16; ++rg) {
                size_t row = rtile + (rg & 3) + 8 * (rg >> 2);
                out[row * N_DIM + col] = (float)acc[mt][nt][rg] * sc + bi;
            }
        }
    }
}

extern "C" void kernel_launch(void* const* d_in, const int* in_sizes, int n_in,
                              void* d_out, int out_size, void* d_ws, size_t ws_size,
                              hipStream_t stream) {
    const float* x        = (const float*)d_in[0];
    const float* weight   = (const float*)d_in[1];
    const float* bias     = (const float*)d_in[2];
    const float* in_scale = (const float*)d_in[3];
    const float* w_scale  = (const float*)d_in[4];
    const float* b_scale  = (const float*)d_in[5];
    float* out = (float*)d_out;

    char* ws = (char*)d_ws;
    const size_t xk = (size_t)M_DIM * K_DIM;
    const size_t wk = (size_t)N_DIM * K_DIM;
    char*  qx     = ws;
    char*  qw     = ws + xk;
    float* oscale = (float*)(ws + xk + wk);
    float* obias  = oscale + N_DIM;

    const int n16 = (int)(xk / 16);   // 1,048,576 = 4096 * 256
    quant_x_kernel<<<4096, 256, 0, stream>>>(x, in_scale, (i32x4*)qx, n16);
    quant_w_kernel<<<4096, 256, 0, stream>>>(weight, w_scale, (i32x4*)qw, n16);
    prep_kernel<<<32, 256, 0, stream>>>(bias, in_scale, w_scale, b_scale, oscale, obias, N_DIM);

    gemm_i8_kernel<<<4096, 256, 0, stream>>>(qx, qw, oscale, obias, out);
}

// Round 10
// 236.135 us; speedup vs baseline: 1.2854x; 1.0729x over previous
//
#include <hip/hip_runtime.h>

typedef int i32x4 __attribute__((ext_vector_type(4)));

#define AS1 __attribute__((address_space(1)))
#define AS3 __attribute__((address_space(3)))

#define M_DIM 8192
#define N_DIM 8192
#define K_DIM 2048
#define NT2 16   // K-tiles of 128 bytes

// ---------------- quantize x: per-tensor scale, 16 elems/thread ----------------
__global__ __launch_bounds__(256) void quant_x_kernel(
    const float* __restrict__ x, const float* __restrict__ in_scale,
    i32x4* __restrict__ qx, int n16)
{
    int idx = blockIdx.x * 256 + threadIdx.x;
    if (idx >= n16) return;
    float s = in_scale[0];
    const float4* xp = reinterpret_cast<const float4*>(x) + (size_t)idx * 4;
    union { char c[16]; i32x4 v; } u;
#pragma unroll
    for (int v4 = 0; v4 < 4; ++v4) {
        float4 f = xp[v4];
        u.c[v4*4+0] = (char)(int)fminf(fmaxf(rintf(f.x / s), -128.f), 127.f);
        u.c[v4*4+1] = (char)(int)fminf(fmaxf(rintf(f.y / s), -128.f), 127.f);
        u.c[v4*4+2] = (char)(int)fminf(fmaxf(rintf(f.z / s), -128.f), 127.f);
        u.c[v4*4+3] = (char)(int)fminf(fmaxf(rintf(f.w / s), -128.f), 127.f);
    }
    qx[idx] = u.v;
}

// ---------------- quantize w: per-row (out-channel) scale ----------------
__global__ __launch_bounds__(256) void quant_w_kernel(
    const float* __restrict__ w, const float* __restrict__ w_scale,
    i32x4* __restrict__ qw, int n16)
{
    int idx = blockIdx.x * 256 + threadIdx.x;
    if (idx >= n16) return;
    float s = w_scale[idx >> 7];   // K=2048 -> 128 threads (of 16 elems) per row
    const float4* wp = reinterpret_cast<const float4*>(w) + (size_t)idx * 4;
    union { char c[16]; i32x4 v; } u;
#pragma unroll
    for (int v4 = 0; v4 < 4; ++v4) {
        float4 f = wp[v4];
        u.c[v4*4+0] = (char)(int)fminf(fmaxf(rintf(f.x / s), -128.f), 127.f);
        u.c[v4*4+1] = (char)(int)fminf(fmaxf(rintf(f.y / s), -128.f), 127.f);
        u.c[v4*4+2] = (char)(int)fminf(fmaxf(rintf(f.z / s), -128.f), 127.f);
        u.c[v4*4+3] = (char)(int)fminf(fmaxf(rintf(f.w / s), -128.f), 127.f);
    }
    qw[idx] = u.v;
}

// ---------------- per-out-channel combined scale + dequantized bias ----------------
__global__ __launch_bounds__(256) void prep_kernel(
    const float* __restrict__ bias, const float* __restrict__ in_scale,
    const float* __restrict__ w_scale, const float* __restrict__ b_scale,
    float* __restrict__ oscale, float* __restrict__ obias, int n)
{
    int i = blockIdx.x * 256 + threadIdx.x;
    if (i >= n) return;
    oscale[i] = in_scale[0] * w_scale[i] * 0.5f;   // W_ALPHA
    float bs = b_scale[i];
    float q = fminf(fmaxf(rintf(bias[i] / bs), -128.f), 127.f);
    obias[i] = q * bs * 0.75f;                      // B_BETA
}

// ---------------- int8 GEMM: 256x256, BK=128B (m201 byte-geometry), dbuf ----------------
// 8 waves (2M x 4N), per-wave 128x64 = 8x4 frags x 2 k-slices of mfma_i32_16x16x64_i8
// = 64 MFMA per wave per staged tile (2x R5 — amortizes each stage/gate round-trip).
// LDS: 2 bufs x (A 32KB + B 32KB) = 128 KiB; rows are 128 B = 8 x 16B slots.
// Swizzle: slot' = slot ^ (row&7) (full 8-slot coverage; R2-validated family),
// inverse-swizzled global source (rule 21), linear global_load_lds dest.
// Per K-tile: 4 phases x {ds_reads; 2-4 stage calls (phases 0-1 only); bar; lgkm0;
// setprio(1); 16 MFMA; setprio(0); bar}; vmcnt(0) gate at end of phase 3 (~3 phases
// after last stage call). Ring safety: stage of t+1 issues after t-1's closing
// barrier, by which point all waves' reads of buffer (t+1)&1 are lgkm-drained.
// NOTE: min-waves-per-EU MUST stay 2 — acc=128 regs; bound of 4 spills (R3: 6x).
__global__ __launch_bounds__(512, 2) void gemm_i8_kernel(
    const char* __restrict__ qx,   // [M][K] int8
    const char* __restrict__ qw,   // [N][K] int8
    const float* __restrict__ oscale,
    const float* __restrict__ obias,
    float* __restrict__ out)       // [M][N] fp32
{
    __shared__ __align__(16) char ldsA[2 * 32768];
    __shared__ __align__(16) char ldsB[2 * 32768];

    const int t    = threadIdx.x;          // 0..511
    const int lane = t & 63;
    const int wid  = t >> 6;               // 0..7
    const int wm   = wid >> 2;             // 0..1
    const int wn   = wid & 3;              // 0..3

    // XCD-aware swizzle: 1024 blocks, 1024 % 8 == 0 -> bijective
    int bid = blockIdx.x;
    int sid = (bid & 7) * 128 + (bid >> 3);
    const size_t brow = (size_t)(sid >> 5) * 256;
    const size_t bcol = (size_t)(sid & 31) * 256;

    // staging: per call, 512 threads cover 64 rows x 128 B (8 KB). Thread t:
    // row (call*64 + t>>3), 16B slot t&7 (linear dest). Global source fetches
    // logical slot (t&7) ^ (row&7) = (t&7) ^ ((t>>3)&7)  (rule 21).
    const int srow  = t >> 3;              // 0..63
    const int lslot = (t & 7) ^ (srow & 7);
    const char* gA = qx + (brow + srow) * K_DIM + lslot * 16;
    const char* gB = qw + (bcol + srow) * K_DIM + lslot * 16;
    char* dstA = ldsA + t * 16;
    char* dstB = ldsB + t * 16;

#define SA_CALL(tt_, c_) __builtin_amdgcn_global_load_lds(                                 \
        (const AS1 unsigned int*)(gA + (tt_) * 128 + (c_) * 64 * K_DIM),                   \
        (AS3 unsigned int*)(dstA + ((tt_) & 1) * 32768 + (c_) * 8192), 16, 0, 0)
#define SB_CALL(tt_, c_) __builtin_amdgcn_global_load_lds(                                 \
        (const AS1 unsigned int*)(gB + (tt_) * 128 + (c_) * 64 * K_DIM),                   \
        (AS3 unsigned int*)(dstB + ((tt_) & 1) * 32768 + (c_) * 8192), 16, 0, 0)

    // frag read offsets: lane reads row r (16-row frag groups; swizzle invariant
    // under +16 rows), slot kk*4+kg swizzled by ^(r&7). frag m = +m*2048 bytes.
    const int lrow = lane & 15;
    const int kg   = lane >> 4;            // 0..3
    const int rA   = wm * 128 + lrow;
    const int rB   = wn * 64 + lrow;
    const int offA0 = rA * 128 + ((kg       ^ (rA & 7)) * 16);   // k-slice 0
    const int offA1 = rA * 128 + (((4 + kg) ^ (rA & 7)) * 16);   // k-slice 1
    const int offB0 = rB * 128 + ((kg       ^ (rB & 7)) * 16);
    const int offB1 = rB * 128 + (((4 + kg) ^ (rB & 7)) * 16);

    i32x4 acc[8][4];
#pragma unroll
    for (int m = 0; m < 8; ++m)
#pragma unroll
        for (int n = 0; n < 4; ++n)
            acc[m][n] = (i32x4){0, 0, 0, 0};

#define MM(m_, n_, a_, b_) acc[m_][n_] = __builtin_amdgcn_mfma_i32_16x16x64_i8((a_), (b_), acc[m_][n_], 0, 0, 0)
#define BAR() do { __builtin_amdgcn_s_barrier(); asm volatile("" ::: "memory"); } while (0)
#define LGKM0() do { asm volatile("s_waitcnt lgkmcnt(0)" ::: "memory"); __builtin_amdgcn_sched_barrier(0); } while (0)

    // prologue: tile 0 fully staged and certified
    SA_CALL(0,0); SA_CALL(0,1); SA_CALL(0,2); SA_CALL(0,3);
    SB_CALL(0,0); SB_CALL(0,1); SB_CALL(0,2); SB_CALL(0,3);
    asm volatile("s_waitcnt vmcnt(0)" ::: "memory");
    BAR();

    for (int tt = 0; tt < NT2; ++tt) {
        const char* bA = ldsA + (tt & 1) * 32768;
        const char* bB = ldsB + (tt & 1) * 32768;
        const bool pf = (tt + 1) < NT2;

        // ---- Phase 0: A m0-3 slice0 + B n0-3 slice0; stage A(t+1); 16 MFMA
        i32x4 a0 = *(const i32x4*)(bA + offA0);
        i32x4 a1 = *(const i32x4*)(bA + offA0 + 2048);
        i32x4 a2 = *(const i32x4*)(bA + offA0 + 4096);
        i32x4 a3 = *(const i32x4*)(bA + offA0 + 6144);
        i32x4 b0 = *(const i32x4*)(bB + offB0);
        i32x4 b1 = *(const i32x4*)(bB + offB0 + 2048);
        i32x4 b2 = *(const i32x4*)(bB + offB0 + 4096);
        i32x4 b3 = *(const i32x4*)(bB + offB0 + 6144);
        if (pf) { SA_CALL(tt+1,0); SA_CALL(tt+1,1); SA_CALL(tt+1,2); SA_CALL(tt+1,3); }
        BAR();
        LGKM0();
        __builtin_amdgcn_s_setprio(1);
        MM(0,0,a0,b0); MM(0,1,a0,b1); MM(0,2,a0,b2); MM(0,3,a0,b3);
        MM(1,0,a1,b0); MM(1,1,a1,b1); MM(1,2,a1,b2); MM(1,3,a1,b3);
        MM(2,0,a2,b0); MM(2,1,a2,b1); MM(2,2,a2,b2); MM(2,3,a2,b3);
        MM(3,0,a3,b0); MM(3,1,a3,b1); MM(3,2,a3,b2); MM(3,3,a3,b3);
        __builtin_amdgcn_s_setprio(0);
        BAR();

        // ---- Phase 1: A m4-7 slice0; stage B(t+1); 16 MFMA
        i32x4 a4 = *(const i32x4*)(bA + offA0 + 8192);
        i32x4 a5 = *(const i32x4*)(bA + offA0 + 10240);
        i32x4 a6 = *(const i32x4*)(bA + offA0 + 12288);
        i32x4 a7 = *(const i32x4*)(bA + offA0 + 14336);
        if (pf) { SB_CALL(tt+1,0); SB_CALL(tt+1,1); SB_CALL(tt+1,2); SB_CALL(tt+1,3); }
        BAR();
        LGKM0();
        __builtin_amdgcn_s_setprio(1);
        MM(4,0,a4,b0); MM(4,1,a4,b1); MM(4,2,a4,b2); MM(4,3,a4,b3);
        MM(5,0,a5,b0); MM(5,1,a5,b1); MM(5,2,a5,b2); MM(5,3,a5,b3);
        MM(6,0,a6,b0); MM(6,1,a6,b1); MM(6,2,a6,b2); MM(6,3,a6,b3);
        MM(7,0,a7,b0); MM(7,1,a7,b1); MM(7,2,a7,b2); MM(7,3,a7,b3);
        __builtin_amdgcn_s_setprio(0);
        BAR();

        // ---- Phase 2: A m0-3 slice1 + B n0-3 slice1; 16 MFMA
        a0 = *(const i32x4*)(bA + offA1);
        a1 = *(const i32x4*)(bA + offA1 + 2048);
        a2 = *(const i32x4*)(bA + offA1 + 4096);
        a3 = *(const i32x4*)(bA + offA1 + 6144);
        b0 = *(const i32x4*)(bB + offB1);
        b1 = *(const i32x4*)(bB + offB1 + 2048);
        b2 = *(const i32x4*)(bB + offB1 + 4096);
        b3 = *(const i32x4*)(bB + offB1 + 6144);
        BAR();
        LGKM0();
        __builtin_amdgcn_s_setprio(1);
        MM(0,0,a0,b0); MM(0,1,a0,b1); MM(0,2,a0,b2); MM(0,3,a0,b3);
        MM(1,0,a1,b0); MM(1,1,a1,b1); MM(1,2,a1,b2); MM(1,3,a1,b3);
        MM(2,0,a2,b0); MM(2,1,a2,b1); MM(2,2,a2,b2); MM(2,3,a2,b3);
        MM(3,0,a3,b0); MM(3,1,a3,b1); MM(3,2,a3,b2); MM(3,3,a3,b3);
        __builtin_amdgcn_s_setprio(0);
        BAR();

        // ---- Phase 3: A m4-7 slice1; 16 MFMA; vmcnt(0) gate; closing barrier
        a4 = *(const i32x4*)(bA + offA1 + 8192);
        a5 = *(const i32x4*)(bA + offA1 + 10240);
        a6 = *(const i32x4*)(bA + offA1 + 12288);
        a7 = *(const i32x4*)(bA + offA1 + 14336);
        BAR();
        LGKM0();
        __builtin_amdgcn_s_setprio(1);
        MM(4,0,a4,b0); MM(4,1,a4,b1); MM(4,2,a4,b2); MM(4,3,a4,b3);
        MM(5,0,a5,b0); MM(5,1,a5,b1); MM(5,2,a5,b2); MM(5,3,a5,b3);
        MM(6,0,a6,b0); MM(6,1,a6,b1); MM(6,2,a6,b2); MM(6,3,a6,b3);
        MM(7,0,a7,b0); MM(7,1,a7,b1); MM(7,2,a7,b2); MM(7,3,a7,b3);
        __builtin_amdgcn_s_setprio(0);
        if (pf) asm volatile("s_waitcnt vmcnt(0)" ::: "memory");  // ~3 phases of cover
        BAR();   // closing barrier doubles as tile t+1's data-visibility gate
    }
#undef SA_CALL
#undef SB_CALL
#undef MM
#undef BAR
#undef LGKM0

    // epilogue: C/D layout col = lane&15, row = (lane>>4)*4 + j
    const int colq = lane & 15;
    const int rowq = lane >> 4;
#pragma unroll
    for (int n = 0; n < 4; ++n) {
        size_t col = bcol + wn * 64 + n * 16 + colq;
        float sc = oscale[col];
        float bi = obias[col];
#pragma unroll
        for (int m = 0; m < 8; ++m) {
            size_t rbase = brow + wm * 128 + m * 16 + (size_t)rowq * 4;
#pragma unroll
            for (int j = 0; j < 4; ++j)
                out[(rbase + j) * N_DIM + col] = (float)acc[m][n][j] * sc + bi;
        }
    }
}

extern "C" void kernel_launch(void* const* d_in, const int* in_sizes, int n_in,
                              void* d_out, int out_size, void* d_ws, size_t ws_size,
                              hipStream_t stream) {
    const float* x        = (const float*)d_in[0];
    const float* weight   = (const float*)d_in[1];
    const float* bias     = (const float*)d_in[2];
    const float* in_scale = (const float*)d_in[3];
    const float* w_scale  = (const float*)d_in[4];
    const float* b_scale  = (const float*)d_in[5];
    float* out = (float*)d_out;

    char* ws = (char*)d_ws;
    const size_t xk = (size_t)M_DIM * K_DIM;
    const size_t wk = (size_t)N_DIM * K_DIM;
    char*  qx     = ws;
    char*  qw     = ws + xk;
    float* oscale = (float*)(ws + xk + wk);
    float* obias  = oscale + N_DIM;

    const int n16 = (int)(xk / 16);   // 1,048,576 = 4096 * 256
    quant_x_kernel<<<4096, 256, 0, stream>>>(x, in_scale, (i32x4*)qx, n16);
    quant_w_kernel<<<4096, 256, 0, stream>>>(weight, w_scale, (i32x4*)qw, n16);
    prep_kernel<<<32, 256, 0, stream>>>(bias, in_scale, w_scale, b_scale, oscale, obias, N_DIM);

    gemm_i8_kernel<<<1024, 512, 0, stream>>>(qx, qw, oscale, obias, out);
}

// Round 11
// 227.235 us; speedup vs baseline: 1.3358x; 1.0392x over previous
//
#include <hip/hip_runtime.h>

typedef int i32x4 __attribute__((ext_vector_type(4)));

#define AS1 __attribute__((address_space(1)))
#define AS3 __attribute__((address_space(3)))

#define M_DIM 8192
#define N_DIM 8192
#define K_DIM 2048
#define NT 32   // K-tiles of 64 bytes

// ---------------- quantize x: per-tensor scale, 16 elems/thread ----------------
__global__ __launch_bounds__(256) void quant_x_kernel(
    const float* __restrict__ x, const float* __restrict__ in_scale,
    i32x4* __restrict__ qx, int n16)
{
    int idx = blockIdx.x * 256 + threadIdx.x;
    if (idx >= n16) return;
    float s = in_scale[0];
    const float4* xp = reinterpret_cast<const float4*>(x) + (size_t)idx * 4;
    union { char c[16]; i32x4 v; } u;
#pragma unroll
    for (int v4 = 0; v4 < 4; ++v4) {
        float4 f = xp[v4];
        u.c[v4*4+0] = (char)(int)fminf(fmaxf(rintf(f.x / s), -128.f), 127.f);
        u.c[v4*4+1] = (char)(int)fminf(fmaxf(rintf(f.y / s), -128.f), 127.f);
        u.c[v4*4+2] = (char)(int)fminf(fmaxf(rintf(f.z / s), -128.f), 127.f);
        u.c[v4*4+3] = (char)(int)fminf(fmaxf(rintf(f.w / s), -128.f), 127.f);
    }
    qx[idx] = u.v;
}

// ---------------- quantize w: per-row (out-channel) scale ----------------
__global__ __launch_bounds__(256) void quant_w_kernel(
    const float* __restrict__ w, const float* __restrict__ w_scale,
    i32x4* __restrict__ qw, int n16)
{
    int idx = blockIdx.x * 256 + threadIdx.x;
    if (idx >= n16) return;
    float s = w_scale[idx >> 7];   // K=2048 -> 128 threads (of 16 elems) per row
    const float4* wp = reinterpret_cast<const float4*>(w) + (size_t)idx * 4;
    union { char c[16]; i32x4 v; } u;
#pragma unroll
    for (int v4 = 0; v4 < 4; ++v4) {
        float4 f = wp[v4];
        u.c[v4*4+0] = (char)(int)fminf(fmaxf(rintf(f.x / s), -128.f), 127.f);
        u.c[v4*4+1] = (char)(int)fminf(fmaxf(rintf(f.y / s), -128.f), 127.f);
        u.c[v4*4+2] = (char)(int)fminf(fmaxf(rintf(f.z / s), -128.f), 127.f);
        u.c[v4*4+3] = (char)(int)fminf(fmaxf(rintf(f.w / s), -128.f), 127.f);
    }
    qw[idx] = u.v;
}

// ---------------- per-out-channel combined scale + dequantized bias ----------------
__global__ __launch_bounds__(256) void prep_kernel(
    const float* __restrict__ bias, const float* __restrict__ in_scale,
    const float* __restrict__ w_scale, const float* __restrict__ b_scale,
    float* __restrict__ oscale, float* __restrict__ obias, int n)
{
    int i = blockIdx.x * 256 + threadIdx.x;
    if (i >= n) return;
    oscale[i] = in_scale[0] * w_scale[i] * 0.5f;   // W_ALPHA
    float bs = b_scale[i];
    float q = fminf(fmaxf(rintf(bias[i] / bs), -128.f), 127.f);
    obias[i] = q * bs * 0.75f;                      // B_BETA
}

// ---------------- int8 GEMM: 128x256 tile, 8 waves of 64x64, 2 blocks/CU ----------------
// The TLP design (R9 showed 3-block overlap works; R6 failed only on registers):
// per-wave 64x64 output = 4x4 frags of mfma_i32_16x16x64_i8 -> acc = 64 VGPR,
// total reg demand ~120 <= 128 -> launch_bounds(512,4) holds 2 blocks/CU WITHOUT
// spilling (unlike R3's 230-reg demand). One block's MFMA covers the other's
// barrier/vmcnt/LDS stalls (m114 mechanism).
// LDS: 2 bufs x (A 8KB + B 16KB) = 48 KiB -> 2 blocks = 96 KiB/CU.
// Swizzle (R2-verified, 0 conflicts): 16B-slot' = slot ^ ((row>>1)&3),
// inverse-swizzled GLOBAL source + linear global_load_lds dest (rule 21).
// Schedule: per tile {stage(t+1) -> 8 ds_read -> 16 MFMA -> vmcnt(0) -> barrier};
// the drain is covered by reads+MFMA (~900cy) and by the co-resident block.
// Ring safety: at tile t's opening barrier every wave's reads of buf (t+1)&1
// (done during tile t-1, before their MFMAs) have completed -> stage(t+1) safe.
__global__ __launch_bounds__(512, 4) void gemm_i8_kernel(
    const char* __restrict__ qx,   // [M][K] int8
    const char* __restrict__ qw,   // [N][K] int8
    const float* __restrict__ oscale,
    const float* __restrict__ obias,
    float* __restrict__ out)       // [M][N] fp32
{
    __shared__ __align__(16) char ldsA[2 * 8192];
    __shared__ __align__(16) char ldsB[2 * 16384];

    const int t    = threadIdx.x;          // 0..511
    const int lane = t & 63;
    const int wid  = t >> 6;               // 0..7
    const int wm   = wid >> 2;             // 0..1 (64-row block of 128)
    const int wn   = wid & 3;              // 0..3 (64-col block of 256)

    // XCD-aware swizzle: 2048 blocks, 2048 % 8 == 0 -> bijective
    int bid = blockIdx.x;
    int sid = (bid & 7) * 256 + (bid >> 3);
    const size_t brow = (size_t)(sid >> 5) * 128;   // 64 M-tiles
    const size_t bcol = (size_t)(sid & 31) * 256;   // 32 N-tiles

    // staging: per call 512 threads cover 128 rows x 64 B. Thread t: row t>>2
    // (B call 1: +128), 16B slot t&3 (linear dest). Global source pre-swizzled:
    // logical slot = (t&3) ^ ((row>>1)&3) = (t&3) ^ ((t>>3)&3)   [row%4 invariant
    // under +128]. (rule 21: inverse-swz source + linear dest + swz read.)
    const int srow  = t >> 2;              // 0..127
    const int lslot = (t & 3) ^ ((t >> 3) & 3);
    const char* gA = qx + (brow + srow) * K_DIM + lslot * 16;
    const char* gB = qw + (bcol + srow) * K_DIM + lslot * 16;
    char* dstA = ldsA + t * 16;
    char* dstB = ldsB + t * 16;

#define STAGE(tt_) do {                                                                   \
    const int bb_ = (tt_) & 1; const int ko_ = (tt_) * 64;                                \
    __builtin_amdgcn_global_load_lds((const AS1 unsigned int*)(gA + ko_),                 \
        (AS3 unsigned int*)(dstA + bb_ * 8192), 16, 0, 0);                                \
    __builtin_amdgcn_global_load_lds((const AS1 unsigned int*)(gB + ko_),                 \
        (AS3 unsigned int*)(dstB + bb_ * 16384), 16, 0, 0);                               \
    __builtin_amdgcn_global_load_lds((const AS1 unsigned int*)(gB + ko_ + 128 * K_DIM),   \
        (AS3 unsigned int*)(dstB + bb_ * 16384 + 8192), 16, 0, 0);                        \
  } while (0)

    // frag read offsets (swizzled): row r, slot kg, ^((r>>1)&3). Frag step = 16
    // rows = +1024 B (swizzle-invariant: +8 in r>>1 == 0 mod 4).
    const int lrow = lane & 15;
    const int kg   = lane >> 4;            // 16B k-group 0..3
    const int rA   = wm * 64 + lrow;
    const int rB   = wn * 64 + lrow;
    const int offA0 = rA * 64 + ((kg ^ ((rA >> 1) & 3)) * 16);
    const int offB0 = rB * 64 + ((kg ^ ((rB >> 1) & 3)) * 16);

    i32x4 acc[4][4];
#pragma unroll
    for (int m = 0; m < 4; ++m)
#pragma unroll
        for (int n = 0; n < 4; ++n)
            acc[m][n] = (i32x4){0, 0, 0, 0};

#define MM(m_, n_, a_, b_) acc[m_][n_] = __builtin_amdgcn_mfma_i32_16x16x64_i8((a_), (b_), acc[m_][n_], 0, 0, 0)
#define BAR() do { __builtin_amdgcn_s_barrier(); asm volatile("" ::: "memory"); } while (0)
#define VMCNT0() asm volatile("s_waitcnt vmcnt(0)" ::: "memory")

    // prologue: tile 0 staged and certified
    STAGE(0);
    VMCNT0();
    BAR();

    for (int tt = 0; tt < NT; ++tt) {
        const char* bA = ldsA + (tt & 1) * 8192;
        const char* bB = ldsB + (tt & 1) * 16384;
        const bool pf = (tt + 1) < NT;

        if (pf) STAGE(tt + 1);

        i32x4 a0 = *(const i32x4*)(bA + offA0);
        i32x4 a1 = *(const i32x4*)(bA + offA0 + 1024);
        i32x4 a2 = *(const i32x4*)(bA + offA0 + 2048);
        i32x4 a3 = *(const i32x4*)(bA + offA0 + 3072);
        i32x4 b0 = *(const i32x4*)(bB + offB0);
        i32x4 b1 = *(const i32x4*)(bB + offB0 + 1024);
        i32x4 b2 = *(const i32x4*)(bB + offB0 + 2048);
        i32x4 b3 = *(const i32x4*)(bB + offB0 + 3072);

        __builtin_amdgcn_s_setprio(1);
        MM(0,0,a0,b0); MM(0,1,a0,b1); MM(0,2,a0,b2); MM(0,3,a0,b3);
        MM(1,0,a1,b0); MM(1,1,a1,b1); MM(1,2,a1,b2); MM(1,3,a1,b3);
        MM(2,0,a2,b0); MM(2,1,a2,b1); MM(2,2,a2,b2); MM(2,3,a2,b3);
        MM(3,0,a3,b0); MM(3,1,a3,b1); MM(3,2,a3,b2); MM(3,3,a3,b3);
        __builtin_amdgcn_s_setprio(0);

        if (pf) {
            VMCNT0();   // covered by this tile's reads+MFMA and by the co-resident block
            BAR();      // certifies tile tt+1; reads of tt done -> stage(tt+2) safe
        }
    }
#undef STAGE
#undef MM
#undef BAR
#undef VMCNT0

    // epilogue: C/D layout col = lane&15, row = (lane>>4)*4 + j
    const int colq = lane & 15;
    const int rowq = lane >> 4;
#pragma unroll
    for (int n = 0; n < 4; ++n) {
        size_t col = bcol + wn * 64 + n * 16 + colq;
        float sc = oscale[col];
        float bi = obias[col];
#pragma unroll
        for (int m = 0; m < 4; ++m) {
            size_t rbase = brow + wm * 64 + m * 16 + (size_t)rowq * 4;
#pragma unroll
            for (int j = 0; j < 4; ++j)
                out[(rbase + j) * N_DIM + col] = (float)acc[m][n][j] * sc + bi;
        }
    }
}

extern "C" void kernel_launch(void* const* d_in, const int* in_sizes, int n_in,
                              void* d_out, int out_size, void* d_ws, size_t ws_size,
                              hipStream_t stream) {
    const float* x        = (const float*)d_in[0];
    const float* weight   = (const float*)d_in[1];
    const float* bias     = (const float*)d_in[2];
    const float* in_scale = (const float*)d_in[3];
    const float* w_scale  = (const float*)d_in[4];
    const float* b_scale  = (const float*)d_in[5];
    float* out = (float*)d_out;

    char* ws = (char*)d_ws;
    const size_t xk = (size_t)M_DIM * K_DIM;
    const size_t wk = (size_t)N_DIM * K_DIM;
    char*  qx     = ws;
    char*  qw     = ws + xk;
    float* oscale = (float*)(ws + xk + wk);
    float* obias  = oscale + N_DIM;

    const int n16 = (int)(xk / 16);   // 1,048,576 = 4096 * 256
    quant_x_kernel<<<4096, 256, 0, stream>>>(x, in_scale, (i32x4*)qx, n16);
    quant_w_kernel<<<4096, 256, 0, stream>>>(weight, w_scale, (i32x4*)qw, n16);
    prep_kernel<<<32, 256, 0, stream>>>(bias, in_scale, w_scale, b_scale, oscale, obias, N_DIM);

    gemm_i8_kernel<<<2048, 512, 0, stream>>>(qx, qw, oscale, obias, out);
}